// Round 4
// baseline (468.289 us; speedup 1.0000x reference)
//
#include <hip/hip_runtime.h>

#define BATCH 16
#define CCH   384
#define NSP   3136
#define NSPP  3200   // padded to multiple of 128
#define OQKV  1152
#define KSPL  5      // split-K for G2: 3200/5 = 640 (10 k-steps)

typedef unsigned short u16;
typedef float  f32x4  __attribute__((ext_vector_type(4)));
typedef __bf16 bf16x8 __attribute__((ext_vector_type(8)));

// counted vmcnt wait: leaves newer loads in flight (T4). "memory" clobber keeps
// LDS reads/writes from crossing it.
#define WAITV(N) asm volatile("s_waitcnt vmcnt(%0)" :: "n"(N) : "memory")
// raw barrier + compile-time fence so ds_read/DMA can't be scheduled across.
#define BARR do { __builtin_amdgcn_s_barrier(); __builtin_amdgcn_sched_barrier(0); } while (0)

__device__ __forceinline__ float bf2f(u16 u) {
  union { unsigned int i; float f; } v; v.i = ((unsigned int)u) << 16; return v.f;
}
__device__ __forceinline__ u16 f2bf(float f) {
  union { float f; unsigned int i; } v; v.f = f;
  unsigned int i = v.i;
  return (u16)((i + 0x7fffu + ((i >> 16) & 1u)) >> 16);
}
__device__ __forceinline__ float rdf(const void* p, long i, bool bf) {
  return bf ? bf2f(((const u16*)p)[i]) : ((const float*)p)[i];
}

// direct global->LDS DMA, 16B per lane. LDS dest is wave-uniform base + lane*16.
__device__ __forceinline__ void gload_lds16(const u16* g, u16* l) {
  __builtin_amdgcn_global_load_lds(
      (const __attribute__((address_space(1))) void*)g,
      (__attribute__((address_space(3))) void*)l, 16, 0, 0);
}

// ---------------- x[b][c][n] -> x_t[b][n][c] bf16, n padded to NSPP ----------
__global__ void transpose_kernel(const void* __restrict__ x, u16* __restrict__ xt,
                                 const u16* __restrict__ probe) {
  const bool bf = (probe[0] == 0x3F80u);
  __shared__ float Ls[32 * 65];
  const int t = threadIdx.x;
  const int n0 = blockIdx.x * 64, c0 = blockIdx.y * 32, b = blockIdx.z;
  if (n0 >= NSP) {  // pure pad tile (3136 = 49*64, tiles never straddle)
    const int n_l = t >> 2, c8 = (t & 3) * 8;
    uint4 zq = make_uint4(0, 0, 0, 0);
    *(uint4*)(xt + ((long)b * NSPP + n0 + n_l) * CCH + c0 + c8) = zq;
    return;
  }
  {
    const int c_l = t >> 3, n8 = (t & 7) * 8;
    const long src = ((long)b * CCH + c0 + c_l) * NSP + n0 + n8;
    float v[8];
    if (bf) {
      union { uint4 q; u16 e[8]; } u; u.q = *(const uint4*)((const u16*)x + src);
      #pragma unroll
      for (int i = 0; i < 8; i++) v[i] = bf2f(u.e[i]);
    } else {
      float4 a = *(const float4*)((const float*)x + src);
      float4 c = *(const float4*)((const float*)x + src + 4);
      v[0]=a.x; v[1]=a.y; v[2]=a.z; v[3]=a.w; v[4]=c.x; v[5]=c.y; v[6]=c.z; v[7]=c.w;
    }
    #pragma unroll
    for (int i = 0; i < 8; i++) Ls[c_l * 65 + n8 + i] = v[i];
  }
  __syncthreads();
  {
    const int n_l = t >> 2, c8 = (t & 3) * 8;
    union { uint4 q; u16 e[8]; } o;
    #pragma unroll
    for (int i = 0; i < 8; i++) o.e[i] = f2bf(Ls[(c8 + i) * 65 + n_l]);
    *(uint4*)(xt + ((long)b * NSPP + n0 + n_l) * CCH + c0 + c8) = o.q;
  }
}

// ---------------- prep: fold BN into qkv weight/bias; convert w_proj ----------
__global__ void prep_kernel(const void* __restrict__ w_qkv, const void* __restrict__ b_qkv,
                            const void* __restrict__ gamma, const void* __restrict__ beta,
                            const void* __restrict__ mean,  const void* __restrict__ var,
                            const void* __restrict__ b_proj, const void* __restrict__ w_proj,
                            u16* __restrict__ w_eff, float* __restrict__ b_eff,
                            float* __restrict__ bproj_f, u16* __restrict__ wp_bf,
                            const u16* __restrict__ probe) {
  const bool bf = (probe[0] == 0x3F80u);
  __shared__ float s_scale[CCH], s_shift[CCH];
  const int tid = threadIdx.x;  // 128
  for (int c = tid; c < CCH; c += 128) {
    float g = rdf(gamma, c, bf), bt = rdf(beta, c, bf);
    float mn = rdf(mean, c, bf), vr = rdf(var, c, bf);
    float sc = g * rsqrtf(vr + 1e-5f);
    s_scale[c] = sc; s_shift[c] = bt - mn * sc;
  }
  __syncthreads();
  const int o = blockIdx.x;
  float part = 0.f;
  for (int c = tid; c < CCH; c += 128) {
    float w = rdf(w_qkv, (long)o * CCH + c, bf);
    w_eff[o * CCH + c] = f2bf(w * s_scale[c]);
    part += w * s_shift[c];
  }
  for (int off = 32; off > 0; off >>= 1) part += __shfl_down(part, off, 64);
  __shared__ float s_part[2];
  if ((tid & 63) == 0) s_part[tid >> 6] = part;
  __syncthreads();
  if (tid == 0) b_eff[o] = rdf(b_qkv, o, bf) + s_part[0] + s_part[1];
  if (o < CCH) {
    for (int c = tid; c < CCH; c += 128)
      wp_bf[o * CCH + c] = f2bf(rdf(w_proj, (long)o * CCH + c, bf));
  }
  if (o == 0) {
    for (int c = tid; c < CCH; c += 128) bproj_f[c] = rdf(b_proj, c, bf);
  }
}

// ---------------- zero fill ---------------------------------------------------
__global__ void zero_kernel(float4* __restrict__ p, long n4) {
  for (long i = (long)blockIdx.x * blockDim.x + threadIdx.x; i < n4;
       i += (long)gridDim.x * blockDim.x)
    p[i] = make_float4(0.f, 0.f, 0.f, 0.f);
}

// ---------------- generic NT GEMM: C(MxN) = A(MxK) @ B(NxK)^T -----------------
// 128x128 tile, 4 waves (2x2), FM=FN=4. DOUBLE-buffered LDS (64KB) with
// counted-vmcnt pipeline (T3/T4): per k-step
//   compute(cur) -> barrier -> stage(t+2 into cur) -> vmcnt(8) -> barrier
// vmcnt(8) waits only the PREVIOUS stage's 8 loads (vmcnt retires in order),
// leaving the just-issued 8 in flight across the barrier -- never drains to 0.
// Staging: global_load_lds dwordx4, linear LDS dest + pre-XOR-swizzled source.
// Bijective XCD swizzle (m204), m fastest within each XCD chunk.
// OUTM: 0 = bf16, 1 = fp32 partial (+kc*sRes when KS>1), 2 = adaptive (probe).
// NCHK: 0 none, 1 = zero-fill cols >= nLim (G1a), 2 = skip store/res >= nLim (G4).
// QKN: fused row sum-of-squares -> atomicAdd into qns[(zb+z)*768 + row].
template<int BM, int BN, int WGM, int WGN, int OUTM, bool BIASM, bool BIASN, bool RES,
         int KS, bool QKN, int NCHK>
__launch_bounds__(256)
__global__ void gemm_nt(const u16* __restrict__ A, const u16* __restrict__ B,
                        void* __restrict__ Cv,
                        const float* __restrict__ biasm, const float* __restrict__ biasn,
                        const void* __restrict__ resv,
                        int K, int lda, int ldb, int ldc,
                        long sA, long sB, long sC, long sRes, int zb, int nLim,
                        float* __restrict__ qns,
                        const u16* __restrict__ probe) {
  constexpr int WM = BM / WGM, WN = BN / WGN;
  constexpr int FM = WM / 16,  FN = WN / 16;
  constexpr int NA = BM / 32,  NB = BN / 32;   // gload_lds per thread: NA+NB = 8
  const bool f32io = (probe[0] != 0x3F80u);
  __shared__ __align__(16) u16 As0[BM * 64];
  __shared__ __align__(16) u16 As1[BM * 64];
  __shared__ __align__(16) u16 Bs0[BN * 64];
  __shared__ __align__(16) u16 Bs1[BN * 64];
  const int tid = threadIdx.x, wave = tid >> 6, lane = tid & 63;
  const int quad = lane >> 4, l16 = lane & 15;
  const int wm = wave / WGN, wn = wave % WGN;
  int z = blockIdx.z, kc = 0;
  if (KS > 1) { kc = z % KS; z /= KS; }
  A += z * sA; B += z * sB;
  const long cOff = (long)(zb + z) * sC;
  const long rOff = (long)(zb + z) * sRes;

  // bijective XCD swizzle (m204): chunk the 2D grid across 8 XCDs, m fastest.
  const int gx = gridDim.x;
  const int tot = gx * gridDim.y;
  const int wg = blockIdx.y * gx + blockIdx.x;
  const int qq = tot >> 3, rr = tot & 7;
  const int xcd = wg & 7, idx = wg >> 3;
  const int nid = (xcd < rr ? xcd * (qq + 1) : rr * (qq + 1) + (xcd - rr) * qq) + idx;
  const int m0 = (nid % gx) * BM, n0 = (nid / gx) * BN;

  const int kLen = K / KS, kBeg = kc * kLen;

  // per-lane staging: u = tid + p*256; row r = u>>3, chunk k8 = u&7.
  // global k-offset pre-XORed so LDS[r][k8] holds chunk (k8^(r&7)) -> swizzled reads.
  const u16* ag[NA];
  const u16* bg[NB];
  #pragma unroll
  for (int p = 0; p < NA; p++) {
    int u = tid + p * 256, r = u >> 3, k8 = u & 7;
    ag[p] = A + (long)(m0 + r) * lda + kBeg + ((k8 ^ (r & 7)) << 3);
  }
  #pragma unroll
  for (int p = 0; p < NB; p++) {
    int u = tid + p * 256, r = u >> 3, k8 = u & 7;
    bg[p] = B + (long)(n0 + r) * ldb + kBeg + ((k8 ^ (r & 7)) << 3);
  }

  f32x4 acc[FM][FN] = {};

  auto stage = [&](u16* dA, u16* dB) {
    #pragma unroll
    for (int p = 0; p < NA; p++) { gload_lds16(ag[p], dA + (p * 256 + wave * 64) * 8); ag[p] += 64; }
    #pragma unroll
    for (int p = 0; p < NB; p++) { gload_lds16(bg[p], dB + (p * 256 + wave * 64) * 8); bg[p] += 64; }
  };
  auto compute = [&](const u16* sAp, const u16* sBp) {
    #pragma unroll
    for (int tt = 0; tt < 2; tt++) {
      bf16x8 af[FM], bfr[FN];
      #pragma unroll
      for (int f = 0; f < FM; f++) {
        int r = wm * WM + f * 16 + l16;
        af[f] = *(const bf16x8*)&sAp[r * 64 + (((tt * 4 + quad) ^ (l16 & 7)) << 3)];
      }
      #pragma unroll
      for (int g = 0; g < FN; g++) {
        int r = wn * WN + g * 16 + l16;
        bfr[g] = *(const bf16x8*)&sBp[r * 64 + (((tt * 4 + quad) ^ (l16 & 7)) << 3)];
      }
      #pragma unroll
      for (int f = 0; f < FM; f++)
        #pragma unroll
        for (int g = 0; g < FN; g++)
          acc[f][g] = __builtin_amdgcn_mfma_f32_16x16x32_bf16(af[f], bfr[g], acc[f][g], 0, 0, 0);
    }
  };

  const int nt = kLen >> 6;   // all uses here: nt in {6, 10}, always even, >= 2
  // prologue: two stages in flight, wait only the first.
  stage(As0, Bs0);
  if (nt > 1) { stage(As1, Bs1); WAITV(8); }
  else        { WAITV(0); }
  BARR;
  int t = 0;
  while (true) {
    compute(As0, Bs0);
    if (++t == nt) break;
    BARR;                                    // all waves done reading buf0
    if (t + 1 < nt) { stage(As0, Bs0); WAITV(8); }  // wait buf1's loads only
    else            { WAITV(0); }
    BARR;                                    // buf1 collectively ready
    compute(As1, Bs1);
    if (++t == nt) break;
    BARR;
    if (t + 1 < nt) { stage(As1, Bs1); WAITV(8); }
    else            { WAITV(0); }
    BARR;
  }

  #pragma unroll
  for (int f = 0; f < FM; f++) {
    #pragma unroll
    for (int reg = 0; reg < 4; reg++) {
      const int mm = m0 + wm * WM + f * 16 + quad * 4 + reg;
      float s2 = 0.f;
      #pragma unroll
      for (int g = 0; g < FN; g++) {
        int nn = n0 + wn * WN + g * 16 + l16;
        float v = acc[f][g][reg];
        if (BIASM) v += biasm[mm];
        if (BIASN) v += biasn[nn];
        if (NCHK == 1 && nn >= nLim) v = 0.f;
        long off = (long)mm * ldc + nn;
        bool live = (NCHK != 2) || (nn < nLim);
        if (RES && live) {
          long ro = rOff + off;
          v += f32io ? ((const float*)resv)[ro] : bf2f(((const u16*)resv)[ro]);
        }
        if (OUTM == 1) {
          long po = cOff + off + ((KS > 1) ? (long)kc * sRes : 0L);
          ((float*)Cv)[po] = v;
        } else if (OUTM == 2) {
          if (live) {
            if (f32io) ((float*)Cv)[cOff + off] = v;
            else       ((u16*)Cv)[cOff + off]   = f2bf(v);
          }
        } else {
          ((u16*)Cv)[cOff + off] = f2bf(v);
        }
        if (QKN) s2 += v * v;
      }
      if (QKN) {
        s2 += __shfl_xor(s2, 1, 16);
        s2 += __shfl_xor(s2, 2, 16);
        s2 += __shfl_xor(s2, 4, 16);
        s2 += __shfl_xor(s2, 8, 16);
        if (l16 == 0) atomicAdd(qns + (long)(zb + z) * 768 + mm, s2);
      }
    }
  }
}

// ---------------- softmax: sum split-K partials, scale by norms+temp ----------
__global__ void softmax_kernel(const float* __restrict__ logits, const float* __restrict__ sums,
                               const void* __restrict__ temp, u16* __restrict__ attn,
                               int zb, const u16* __restrict__ probe) {
  const bool bfm = (probe[0] == 0x3F80u);
  const int c = blockIdx.x, b = blockIdx.y;
  // logits layout: [b][kc][c][d]
  const long base = ((long)b * KSPL) * (CCH * CCH) + (long)c * CCH;
  const float rq = 1.f / fmaxf(sqrtf(sums[(zb + b) * 768 + c]), 1e-12f);
  const float T = rdf(temp, 0, bfm);
  const int tid = threadIdx.x;  // 128
  float v[3]; float mx = -1e30f;
  #pragma unroll
  for (int j = 0; j < 3; j++) {
    int d = tid + j * 128;
    float lv = 0.f;
    #pragma unroll
    for (int kc = 0; kc < KSPL; kc++) lv += logits[base + (long)kc * CCH * CCH + d];
    float rd = 1.f / fmaxf(sqrtf(sums[(zb + b) * 768 + 384 + d]), 1e-12f);
    float xv = lv * rq * rd * T;
    v[j] = xv; mx = fmaxf(mx, xv);
  }
  for (int off = 32; off > 0; off >>= 1) mx = fmaxf(mx, __shfl_down(mx, off, 64));
  __shared__ float sm[2];
  if ((tid & 63) == 0) sm[tid >> 6] = mx;
  __syncthreads();
  mx = fmaxf(sm[0], sm[1]);
  float s = 0.f;
  #pragma unroll
  for (int j = 0; j < 3; j++) { v[j] = __expf(v[j] - mx); s += v[j]; }
  for (int off = 32; off > 0; off >>= 1) s += __shfl_down(s, off, 64);
  __shared__ float ss[2];
  if ((tid & 63) == 0) ss[tid >> 6] = s;
  __syncthreads();
  s = ss[0] + ss[1];
  const float inv = 1.f / s;
  u16* arow = attn + ((long)b * CCH + c) * CCH;
  #pragma unroll
  for (int j = 0; j < 3; j++) arow[tid + j * 128] = f2bf(v[j] * inv);
}

// ---------------- launcher ----------------------------------------------------
extern "C" void kernel_launch(void* const* d_in, const int* in_sizes, int n_in,
                              void* d_out, int out_size, void* d_ws, size_t ws_size,
                              hipStream_t stream) {
  const void* x      = d_in[0];
  const void* w_qkv  = d_in[1];
  const void* b_qkv  = d_in[2];
  const void* w_proj = d_in[3];
  const void* b_proj = d_in[4];
  const void* gamma  = d_in[5];
  const void* beta   = d_in[6];
  const void* mean   = d_in[7];
  const void* var    = d_in[8];
  const void* temp   = d_in[9];
  const u16* probe = (const u16*)gamma;  // 1.0: bf16 -> 0x3F80, fp32 low word -> 0x0000

  const size_t SZ_XT    = (size_t)BATCH * NSPP * CCH * 2;   // 39.3 MB
  const size_t SZ_WEFF  = (size_t)OQKV * CCH * 2;
  const size_t SZ_WPBF  = (size_t)CCH * CCH * 2;
  const size_t SZ_BEFF  = (size_t)OQKV * 4;
  const size_t SZ_BPROJ = (size_t)CCH * 4;
  const size_t SZ_SUMS  = (size_t)BATCH * 768 * 4;
  const size_t SZ_QK_B  = (size_t)768 * NSPP * 2;           // 4.92 MB
  const size_t SZ_VT_B  = (size_t)NSPP * CCH * 2;           // 2.46 MB
  const size_t SZ_FT_B  = (size_t)NSPP * CCH * 2;           // 2.46 MB
  const size_t SZ_LOG_B = (size_t)KSPL * CCH * CCH * 4;     // 2.95 MB
  const size_t SZ_ATT_B = (size_t)CCH * CCH * 2;
  const size_t P = SZ_QK_B + SZ_VT_B + SZ_FT_B + SZ_LOG_B + SZ_ATT_B;
  const size_t FIXED = SZ_XT + SZ_WEFF + SZ_WPBF + SZ_BEFF + SZ_BPROJ + SZ_SUMS;

  long chunk = 1;
  if (ws_size >= FIXED + P) {
    chunk = (long)((ws_size - FIXED) / P);
    if (chunk > BATCH) chunk = BATCH;
    if (chunk < 1) chunk = 1;
  }

  char* ws = (char*)d_ws;
  u16*   xt      = (u16*)ws;   ws += SZ_XT;
  u16*   w_eff   = (u16*)ws;   ws += SZ_WEFF;
  u16*   wp_bf   = (u16*)ws;   ws += SZ_WPBF;
  float* b_eff   = (float*)ws; ws += SZ_BEFF;
  float* bproj_f = (float*)ws; ws += SZ_BPROJ;
  float* sums    = (float*)ws; ws += SZ_SUMS;
  float* logits  = (float*)ws; ws += SZ_LOG_B * chunk;
  u16*   attn    = (u16*)ws;   ws += SZ_ATT_B * chunk;
  u16*   qk      = (u16*)ws;   ws += SZ_QK_B * chunk;
  u16*   v_t     = (u16*)ws;   ws += SZ_VT_B * chunk;
  u16*   fused_t = (u16*)ws;   ws += SZ_FT_B * chunk;

  transpose_kernel<<<dim3(NSPP / 64, CCH / 32, BATCH), dim3(256), 0, stream>>>(x, xt, probe);
  prep_kernel<<<dim3(OQKV), dim3(128), 0, stream>>>(
      w_qkv, b_qkv, gamma, beta, mean, var, b_proj, w_proj,
      w_eff, b_eff, bproj_f, wp_bf, probe);
  zero_kernel<<<dim3(12), dim3(256), 0, stream>>>((float4*)sums, (long)BATCH * 768 / 4);

  const long sX  = (long)CCH * NSP;
  const long sXT = (long)NSPP * CCH;
  const long sQK = (long)768 * NSPP;
  const long sVT = (long)NSPP * CCH;
  const long sFT = (long)NSPP * CCH;
  const long sLG = (long)KSPL * CCH * CCH;   // per-batch stride of partial logits
  const long sAT = (long)CCH * CCH;

  for (long b0 = 0; b0 < BATCH; b0 += chunk) {
    const int nb = (int)((BATCH - b0) < chunk ? (BATCH - b0) : chunk);
    const u16* xtb = xt + b0 * sXT;

    // G1a: qk[o][n] = w_eff[0:768] @ x_t^T + b_eff; zero pad cols; fused sumsq
    gemm_nt<128, 128, 2, 2, 0, true, false, false, 1, true, 1>
        <<<dim3(6, 25, nb), dim3(256), 0, stream>>>(
        w_eff, xtb, qk, b_eff, nullptr, nullptr,
        CCH, CCH, CCH, NSPP, 0L, sXT, sQK, 0L, (int)b0, NSP, sums, probe);

    // G1b: v_t[n][d] = x_t @ w_v^T + b_v[d]
    gemm_nt<128, 128, 2, 2, 0, false, true, false, 1, false, 0>
        <<<dim3(25, 3, nb), dim3(256), 0, stream>>>(
        xtb, w_eff + (long)768 * CCH, v_t, nullptr, b_eff + 768, nullptr,
        CCH, CCH, CCH, CCH, sXT, 0L, sVT, 0L, 0, 0, nullptr, probe);

    // G2: partial logits[kc][c][d] = q @ k^T (fp32, split-K=5, padded K=3200)
    gemm_nt<128, 128, 2, 2, 1, false, false, false, KSPL, false, 0>
        <<<dim3(3, 3, nb * KSPL), dim3(256), 0, stream>>>(
        qk, qk + (long)CCH * NSPP, logits, nullptr, nullptr, nullptr,
        NSPP, NSPP, NSPP, CCH, sQK, sQK, sLG, (long)CCH * CCH, 0, 0, nullptr, probe);

    // softmax: sum partials, scale by 1/(|q||k|) * T, exp-normalize -> bf16 attn
    softmax_kernel<<<dim3(CCH, nb), dim3(128), 0, stream>>>(
        logits, sums, temp, attn, (int)b0, probe);

    // G3: fused_t[n][c] = v_t @ attn^T
    gemm_nt<128, 128, 2, 2, 0, false, false, false, 1, false, 0>
        <<<dim3(25, 3, nb), dim3(256), 0, stream>>>(
        v_t, attn, fused_t, nullptr, nullptr, nullptr,
        CCH, CCH, CCH, CCH, sVT, sAT, sFT, 0L, 0, 0, nullptr, probe);

    // G4: out[o][n] = wp @ fused_t^T + bproj + x  (store/res only n < 3136)
    gemm_nt<128, 128, 2, 2, 2, true, false, true, 1, false, 2>
        <<<dim3(3, 25, nb), dim3(256), 0, stream>>>(
        wp_bf, fused_t, d_out, bproj_f, nullptr, x,
        CCH, CCH, CCH, NSP, 0L, sFT, sX, sX, (int)b0, NSP, nullptr, probe);
  }
}

// Round 5
// 402.978 us; speedup vs baseline: 1.1621x; 1.1621x over previous
//
#include <hip/hip_runtime.h>

#define BATCH 16
#define CCH   384
#define NSP   3136
#define NSPP  3200   // xt rows padded to multiple of 128

typedef unsigned short u16;
typedef float  f32x4  __attribute__((ext_vector_type(4)));
typedef __bf16 bf16x8 __attribute__((ext_vector_type(8)));

__device__ __forceinline__ float bf2f(u16 u) {
  union { unsigned int i; float f; } v; v.i = ((unsigned int)u) << 16; return v.f;
}
__device__ __forceinline__ u16 f2bf(float f) {
  union { float f; unsigned int i; } v; v.f = f;
  unsigned int i = v.i;
  return (u16)((i + 0x7fffu + ((i >> 16) & 1u)) >> 16);
}
__device__ __forceinline__ float rdf(const void* p, long i, bool bf) {
  return bf ? bf2f(((const u16*)p)[i]) : ((const float*)p)[i];
}

// direct global->LDS DMA, 16B per lane. LDS dest is wave-uniform base + lane*16.
__device__ __forceinline__ void gload_lds16(const u16* g, u16* l) {
  __builtin_amdgcn_global_load_lds(
      (const __attribute__((address_space(1))) void*)g,
      (__attribute__((address_space(3))) void*)l, 16, 0, 0);
}

// ------- x[b][c][n] -> xt[b][n][c] bf16 (n padded to NSPP) AND xbf[b][c][n] ---
__global__ void transpose_kernel(const void* __restrict__ x, u16* __restrict__ xt,
                                 u16* __restrict__ xbf, const u16* __restrict__ probe) {
  const bool bf = (probe[0] == 0x3F80u);
  __shared__ float Ls[32 * 65];
  const int t = threadIdx.x;
  const int n0 = blockIdx.x * 64, c0 = blockIdx.y * 32, b = blockIdx.z;
  if (n0 >= NSP) {  // pure pad tile (3136 = 49*64, tiles never straddle)
    const int n_l = t >> 2, c8 = (t & 3) * 8;
    uint4 zq = make_uint4(0, 0, 0, 0);
    *(uint4*)(xt + ((long)b * NSPP + n0 + n_l) * CCH + c0 + c8) = zq;
    return;
  }
  {
    const int c_l = t >> 3, n8 = (t & 7) * 8;
    const long src = ((long)b * CCH + c0 + c_l) * NSP + n0 + n8;
    float v[8];
    if (bf) {
      union { uint4 q; u16 e[8]; } u; u.q = *(const uint4*)((const u16*)x + src);
      #pragma unroll
      for (int i = 0; i < 8; i++) v[i] = bf2f(u.e[i]);
    } else {
      float4 a = *(const float4*)((const float*)x + src);
      float4 c = *(const float4*)((const float*)x + src + 4);
      v[0]=a.x; v[1]=a.y; v[2]=a.z; v[3]=a.w; v[4]=c.x; v[5]=c.y; v[6]=c.z; v[7]=c.w;
    }
    union { uint4 q; u16 e[8]; } ob;
    #pragma unroll
    for (int i = 0; i < 8; i++) { ob.e[i] = f2bf(v[i]); Ls[c_l * 65 + n8 + i] = v[i]; }
    *(uint4*)(xbf + src) = ob.q;   // bf16 copy in native [c][n] layout (for Gram)
  }
  __syncthreads();
  {
    const int n_l = t >> 2, c8 = (t & 3) * 8;
    union { uint4 q; u16 e[8]; } o;
    #pragma unroll
    for (int i = 0; i < 8; i++) o.e[i] = f2bf(Ls[(c8 + i) * 65 + n_l]);
    *(uint4*)(xt + ((long)b * NSPP + n0 + n_l) * CCH + c0 + c8) = o.q;
  }
}

// ------- prep: BN-fold qkv weights; doubled-column (hi/lo K) weight copies ----
__global__ void prep_kernel(const void* __restrict__ w_qkv, const void* __restrict__ b_qkv,
                            const void* __restrict__ gamma, const void* __restrict__ beta,
                            const void* __restrict__ mean,  const void* __restrict__ var,
                            const void* __restrict__ b_proj, const void* __restrict__ w_proj,
                            u16* __restrict__ w_eff, float* __restrict__ b_eff,
                            float* __restrict__ bproj_f,
                            unsigned* __restrict__ w2qk, unsigned* __restrict__ wp2,
                            u16* __restrict__ wvT,
                            const u16* __restrict__ probe) {
  const bool bf = (probe[0] == 0x3F80u);
  __shared__ float s_scale[CCH], s_shift[CCH];
  const int tid = threadIdx.x;  // 128
  for (int c = tid; c < CCH; c += 128) {
    float g = rdf(gamma, c, bf), bt = rdf(beta, c, bf);
    float mn = rdf(mean, c, bf), vr = rdf(var, c, bf);
    float sc = g * rsqrtf(vr + 1e-5f);
    s_scale[c] = sc; s_shift[c] = bt - mn * sc;
  }
  __syncthreads();
  const int o = blockIdx.x;  // [0,1152)
  float part = 0.f;
  for (int c = tid; c < CCH; c += 128) {
    float w = rdf(w_qkv, (long)o * CCH + c, bf);
    u16 wv = f2bf(w * s_scale[c]);
    w_eff[(long)o * CCH + c] = wv;
    if (o < 768) w2qk[(long)o * CCH + c] = (unsigned)wv | ((unsigned)wv << 16);
    else         wvT[(long)c * CCH + (o - 768)] = wv;   // Wv^T
    part += w * s_shift[c];
  }
  for (int off = 32; off > 0; off >>= 1) part += __shfl_down(part, off, 64);
  __shared__ float s_part[2];
  if ((tid & 63) == 0) s_part[tid >> 6] = part;
  __syncthreads();
  if (tid == 0) b_eff[o] = rdf(b_qkv, o, bf) + s_part[0] + s_part[1];
  if (o < CCH) {
    for (int c = tid; c < CCH; c += 128) {
      u16 pv = f2bf(rdf(w_proj, (long)o * CCH + c, bf));
      wp2[(long)o * CCH + c] = (unsigned)pv | ((unsigned)pv << 16);
    }
  }
  if (o == 0) {
    for (int c = tid; c < CCH; c += 128) bproj_f[c] = rdf(b_proj, c, bf);
  }
}

// ------- zero fill ------------------------------------------------------------
__global__ void zero_kernel(float4* __restrict__ p, long n4) {
  for (long i = (long)blockIdx.x * blockDim.x + threadIdx.x; i < n4;
       i += (long)gridDim.x * blockDim.x)
    p[i] = make_float4(0.f, 0.f, 0.f, 0.f);
}

// ------- generic NT GEMM: C(MxN) = A(MxK) @ B(NxK)^T --------------------------
// Round-3 proven loop: single-buffer, global_load_lds dwordx4, pre-XOR-swizzled
// source, 2 barriers/k-step. XCD-bijective swizzle.
// OUTM: 0 bf16 | 1 fp32 (+kc*sRes partial when ks>1) | 2 adaptive | 4 split-bf16
//       (hi,lo u16 pair packed in u32; ldc/sC in u32 units).
// NCHK: 0 none | 2 skip store/res for nn>=nLim | 3 skip store for mm>=nLim.
// EPIL: row dot  qns[(zb+z)*768+mm] += sum_nn v * epW[mm*384+nn]   (norms).
// SUMX: fused A-row sums (n0==0 blocks) -> sxp[z*384+row]          (Gram).
// SYMM: skip blocks with n0 > m0 (symmetric output; consumer mirrors).
template<int BM, int BN, int WGM, int WGN, int OUTM, bool BIASM, bool RES,
         int NCHK, bool EPIL, bool SUMX, bool SYMM>
__launch_bounds__(256)
__global__ void gemm_nt(const u16* __restrict__ A, const u16* __restrict__ B,
                        void* __restrict__ Cv,
                        const float* __restrict__ biasm,
                        const void* __restrict__ resv,
                        int K, int lda, int ldb, int ldc,
                        long sA, long sB, long sC, long sRes,
                        int zb, int nLim, int ks, int sBM,
                        float* __restrict__ qns, const u16* __restrict__ epW,
                        float* __restrict__ sxp,
                        const u16* __restrict__ probe) {
  constexpr int WM = BM / WGM, WN = BN / WGN;
  constexpr int FM = WM / 16,  FN = WN / 16;
  constexpr int NA = BM / 32,  NB = BN / 32;
  const bool f32io = (probe[0] != 0x3F80u);
  __shared__ __align__(16) u16 As[BM * 64];
  __shared__ __align__(16) u16 Bs[BN * 64];
  const int tid = threadIdx.x, wave = tid >> 6, lane = tid & 63;
  const int quad = lane >> 4, l16 = lane & 15;
  const int wm = wave / WGN, wn = wave % WGN;
  int z = blockIdx.z, kc = 0;
  if (ks > 1) { kc = z % ks; z /= ks; }
  A += z * sA; B += z * sB;
  const long cOff = (long)(zb + z) * sC;
  const long rOff = (long)(zb + z) * sRes;

  const int gx = gridDim.x;
  const int tot = gx * gridDim.y;
  const int wg = blockIdx.y * gx + blockIdx.x;
  const int qq = tot >> 3, rr = tot & 7;
  const int xcd = wg & 7, idx = wg >> 3;
  const int nid = (xcd < rr ? xcd * (qq + 1) : rr * (qq + 1) + (xcd - rr) * qq) + idx;
  const int m0 = (nid % gx) * BM, n0 = (nid / gx) * BN;
  if (SYMM && n0 > m0) return;

  const int kLen = K / ks, kBeg = kc * kLen;

  const u16* ag[NA];
  const u16* bg[NB];
  #pragma unroll
  for (int p = 0; p < NA; p++) {
    int u = tid + p * 256, r = u >> 3, k8 = u & 7;
    ag[p] = A + (long)(m0 + r) * lda + kBeg + ((k8 ^ (r & 7)) << 3);
  }
  #pragma unroll
  for (int p = 0; p < NB; p++) {
    int u = tid + p * 256, r = u >> 3, k8 = u & 7;
    bg[p] = B + (long)(n0 + r) * ldb + kBeg + ((k8 ^ (r & 7)) << 3);
  }

  f32x4 acc[FM][FN] = {};
  float rs[FM] = {};   // SUMX accumulators

  const int nt = kLen >> 6;
  for (int t = 0; t < nt; t++) {
    #pragma unroll
    for (int p = 0; p < NA; p++) { gload_lds16(ag[p], &As[(p * 256 + wave * 64) * 8]); ag[p] += 64; }
    #pragma unroll
    for (int p = 0; p < NB; p++) { gload_lds16(bg[p], &Bs[(p * 256 + wave * 64) * 8]); bg[p] += 64; }
    __syncthreads();

    #pragma unroll
    for (int tt = 0; tt < 2; tt++) {
      bf16x8 af[FM], bfr[FN];
      #pragma unroll
      for (int f = 0; f < FM; f++) {
        int r = wm * WM + f * 16 + l16;
        af[f] = *(const bf16x8*)&As[r * 64 + (((tt * 4 + quad) ^ (l16 & 7)) << 3)];
      }
      #pragma unroll
      for (int g = 0; g < FN; g++) {
        int r = wn * WN + g * 16 + l16;
        bfr[g] = *(const bf16x8*)&Bs[r * 64 + (((tt * 4 + quad) ^ (l16 & 7)) << 3)];
      }
      if (SUMX) {
        if (n0 == 0 && wn == 0) {
          #pragma unroll
          for (int f = 0; f < FM; f++)
            #pragma unroll
            for (int j = 0; j < 8; j++) rs[f] += (float)af[f][j];
        }
      }
      #pragma unroll
      for (int f = 0; f < FM; f++)
        #pragma unroll
        for (int g = 0; g < FN; g++)
          acc[f][g] = __builtin_amdgcn_mfma_f32_16x16x32_bf16(af[f], bfr[g], acc[f][g], 0, 0, 0);
    }
    __syncthreads();
  }

  if (SUMX) {
    if (n0 == 0 && wn == 0) {
      #pragma unroll
      for (int f = 0; f < FM; f++) {
        float r = rs[f];
        r += __shfl_xor(r, 16, 64);
        r += __shfl_xor(r, 32, 64);
        if (quad == 0) atomicAdd(sxp + (long)z * CCH + m0 + wm * WM + f * 16 + l16, r);
      }
    }
  }

  #pragma unroll
  for (int f = 0; f < FM; f++) {
    #pragma unroll
    for (int reg = 0; reg < 4; reg++) {
      const int mm = m0 + wm * WM + f * 16 + quad * 4 + reg;
      float s2 = 0.f;
      #pragma unroll
      for (int g = 0; g < FN; g++) {
        int nn = n0 + wn * WN + g * 16 + l16;
        float v = acc[f][g][reg];
        if (BIASM) v += biasm[(long)(zb + z) * sBM + mm];
        long off = (long)mm * ldc + nn;
        bool live = true;
        if (NCHK == 2) live = (nn < nLim);
        if (NCHK == 3) live = (mm < nLim);
        if (RES && live) {
          long ro = rOff + off;
          v += f32io ? ((const float*)resv)[ro] : bf2f(((const u16*)resv)[ro]);
        }
        if (EPIL) s2 += v * bf2f(epW[(long)mm * CCH + nn]);
        if (OUTM == 1) {
          ((float*)Cv)[cOff + off + (long)kc * sRes] = v;
        } else if (OUTM == 2) {
          if (live) {
            if (f32io) ((float*)Cv)[cOff + off] = v;
            else       ((u16*)Cv)[cOff + off]   = f2bf(v);
          }
        } else if (OUTM == 4) {
          if (live) {
            u16 hi = f2bf(v);
            u16 lo = f2bf(v - bf2f(hi));
            ((unsigned*)Cv)[cOff + off] = (unsigned)hi | ((unsigned)lo << 16);
          }
        } else {
          if (live) ((u16*)Cv)[cOff + off] = f2bf(v);
        }
      }
      if (EPIL) {
        s2 += __shfl_xor(s2, 1, 16);
        s2 += __shfl_xor(s2, 2, 16);
        s2 += __shfl_xor(s2, 4, 16);
        s2 += __shfl_xor(s2, 8, 16);
        if (l16 == 0) atomicAdd(qns + (long)(zb + z) * 768 + mm, s2);
      }
    }
  }
}

// ------- Gram reduce: sum split-K partials (mirror lower block-triangle),
//         emit split-bf16 (hi|lo u32) symmetric G ------------------------------
__global__ void greduce_kernel(const float* __restrict__ Gp, unsigned* __restrict__ Gs,
                               int kspl) {
  const int b = blockIdx.y;
  const int idx = blockIdx.x * 256 + threadIdx.x;  // < 384*384
  const int r = idx / CCH, c = idx % CCH;
  const long e = ((r >> 7) >= (c >> 7)) ? ((long)r * CCH + c) : ((long)c * CCH + r);
  const long base = (long)b * kspl * (CCH * CCH);
  float s = 0.f;
  for (int k = 0; k < kspl; k++) s += Gp[base + (long)k * (CCH * CCH) + e];
  u16 hi = f2bf(s);
  u16 lo = f2bf(s - bf2f(hi));
  Gs[(long)b * (CCH * CCH) + idx] = (unsigned)hi | ((unsigned)lo << 16);
}

// ------- u[b][m] = sum_k w_eff[m][k] * sx[b][k]   (m in [0,768)) --------------
__global__ void ugemv_kernel(const u16* __restrict__ w_eff, const float* __restrict__ sx,
                             float* __restrict__ u) {
  const int m = blockIdx.x, b = blockIdx.y, l = threadIdx.x;  // 64
  float s = 0.f;
  for (int k = l; k < CCH; k += 64) s += bf2f(w_eff[(long)m * CCH + k]) * sx[b * CCH + k];
  for (int off = 32; off > 0; off >>= 1) s += __shfl_down(s, off, 64);
  if (l == 0) u[b * 768 + m] = s;
}

// ------- cvec[b][o] = sum_c wp[o][c]*av[b][c] + bproj[o] ----------------------
__global__ void cgemv_kernel(const unsigned* __restrict__ wp2, const float* __restrict__ av,
                             const float* __restrict__ bproj, float* __restrict__ cvec) {
  const int o = blockIdx.x, b = blockIdx.y, l = threadIdx.x;  // 64
  float s = 0.f;
  for (int c = l; c < CCH; c += 64)
    s += bf2f((u16)(wp2[(long)o * CCH + c] & 0xffffu)) * av[b * CCH + c];
  for (int off = 32; off > 0; off >>= 1) s += __shfl_down(s, off, 64);
  if (l == 0) cvec[b * CCH + o] = s + bproj[o];
}

// ------- softmax over d with bias rank-1 terms + norm/temperature scaling -----
__global__ void softmax_kernel(const float* __restrict__ Lg, const float* __restrict__ qn2,
                               const float* __restrict__ u, const float* __restrict__ beff,
                               const void* __restrict__ temp,
                               u16* __restrict__ attn, float* __restrict__ av,
                               const u16* __restrict__ probe) {
  const bool bfm = (probe[0] == 0x3F80u);
  const int c = blockIdx.x, b = blockIdx.y, tid = threadIdx.x;  // 128
  const float* row = Lg + ((long)b * CCH + c) * CCH;
  const float beq = beff[c], uq = u[b * 768 + c];
  const float qn = qn2[b * 768 + c] + 2.f * beq * uq + 3136.f * beq * beq;
  const float rq = 1.f / fmaxf(sqrtf(fmaxf(qn, 0.f)), 1e-12f);
  const float T = rdf(temp, 0, bfm);
  float v[3]; float mx = -1e30f;
  #pragma unroll
  for (int j = 0; j < 3; j++) {
    int d = tid + j * 128;
    float bek = beff[384 + d], uk = u[b * 768 + 384 + d];
    float kn = qn2[b * 768 + 384 + d] + 2.f * bek * uk + 3136.f * bek * bek;
    float rd = 1.f / fmaxf(sqrtf(fmaxf(kn, 0.f)), 1e-12f);
    float lg = row[d] + uq * bek + beq * uk + 3136.f * beq * bek;
    v[j] = lg * rq * rd * T;
    mx = fmaxf(mx, v[j]);
  }
  for (int off = 32; off > 0; off >>= 1) mx = fmaxf(mx, __shfl_down(mx, off, 64));
  __shared__ float sm[2];
  if ((tid & 63) == 0) sm[tid >> 6] = mx;
  __syncthreads();
  mx = fmaxf(sm[0], sm[1]);
  float s = 0.f;
  #pragma unroll
  for (int j = 0; j < 3; j++) { v[j] = __expf(v[j] - mx); s += v[j]; }
  for (int off = 32; off > 0; off >>= 1) s += __shfl_down(s, off, 64);
  __shared__ float ss[2];
  if ((tid & 63) == 0) ss[tid >> 6] = s;
  __syncthreads();
  s = ss[0] + ss[1];
  const float inv = 1.f / s;
  float avp = 0.f;
  u16* arow = attn + ((long)b * CCH + c) * CCH;
  #pragma unroll
  for (int j = 0; j < 3; j++) {
    float p = v[j] * inv;
    arow[tid + j * 128] = f2bf(p);
    avp += p * beff[768 + tid + j * 128];
  }
  for (int off = 32; off > 0; off >>= 1) avp += __shfl_down(avp, off, 64);
  __shared__ float sa[2];
  if ((tid & 63) == 0) sa[tid >> 6] = avp;
  __syncthreads();
  if (tid == 0) av[b * CCH + c] = sa[0] + sa[1];
}

// ------- launcher -------------------------------------------------------------
extern "C" void kernel_launch(void* const* d_in, const int* in_sizes, int n_in,
                              void* d_out, int out_size, void* d_ws, size_t ws_size,
                              hipStream_t stream) {
  const void* x      = d_in[0];
  const void* w_qkv  = d_in[1];
  const void* b_qkv  = d_in[2];
  const void* w_proj = d_in[3];
  const void* b_proj = d_in[4];
  const void* gamma  = d_in[5];
  const void* beta   = d_in[6];
  const void* mean   = d_in[7];
  const void* var    = d_in[8];
  const void* temp   = d_in[9];
  const u16* probe = (const u16*)gamma;  // bf16 1.0 -> 0x3F80; fp32 low word -> 0

  const size_t SZ_XT   = (size_t)BATCH * NSPP * CCH * 2;       // 39.3 MB
  const size_t SZ_XBF  = (size_t)BATCH * CCH * NSP * 2;        // 38.5 MB
  const size_t SZ_WEFF = (size_t)1152 * CCH * 2;
  const size_t SZ_W2QK = (size_t)768 * CCH * 4;                // u32 dup pairs
  const size_t SZ_WP2  = (size_t)CCH * CCH * 4;
  const size_t SZ_WVT  = (size_t)CCH * CCH * 2;
  const size_t SZ_BEFF = (size_t)1152 * 4;
  const size_t SZ_BPRJ = (size_t)CCH * 4;
  const size_t SZ_SUMS = (size_t)BATCH * (CCH + 768) * 4;      // sx then qn2
  const size_t SZ_U    = (size_t)BATCH * 768 * 4;
  const size_t SZ_AV   = (size_t)BATCH * CCH * 4;
  const size_t SZ_CV   = (size_t)BATCH * CCH * 4;
  const size_t SZ_MM   = (size_t)BATCH * CCH * CCH;            // 384x384 per b, x1B unit
  // fixed layout (sans Gp):
  const size_t FIXED = SZ_XT + SZ_XBF + SZ_WEFF + SZ_W2QK + SZ_WP2 + SZ_WVT +
                       SZ_BEFF + SZ_BPRJ + SZ_SUMS + SZ_U + SZ_AV + SZ_CV +
                       SZ_MM * 4 /*Gs*/ + SZ_MM * 4 /*Ts*/ + SZ_MM * 4 /*L*/ +
                       SZ_MM * 2 /*attn*/ + SZ_MM * 4 /*RTs*/ + SZ_MM * 2 /*Mb*/;
  int kspl = 7;  // must divide 49 k-steps
  if (ws_size < FIXED + (size_t)BATCH * 7 * CCH * CCH * 4) kspl = 1;

  char* ws = (char*)d_ws;
  u16*      xt    = (u16*)ws;      ws += SZ_XT;
  u16*      xbf   = (u16*)ws;      ws += SZ_XBF;
  u16*      w_eff = (u16*)ws;      ws += SZ_WEFF;
  unsigned* w2qk  = (unsigned*)ws; ws += SZ_W2QK;
  unsigned* wp2   = (unsigned*)ws; ws += SZ_WP2;
  u16*      wvT   = (u16*)ws;      ws += SZ_WVT;
  float*    b_eff = (float*)ws;    ws += SZ_BEFF;
  float*    bproj = (float*)ws;    ws += SZ_BPRJ;
  float*    sx    = (float*)ws;    ws += (size_t)BATCH * CCH * 4;
  float*    qn2   = (float*)ws;    ws += (size_t)BATCH * 768 * 4;
  float*    u     = (float*)ws;    ws += SZ_U;
  float*    av    = (float*)ws;    ws += SZ_AV;
  float*    cvec  = (float*)ws;    ws += SZ_CV;
  unsigned* Gs    = (unsigned*)ws; ws += SZ_MM * 4;
  unsigned* Ts    = (unsigned*)ws; ws += SZ_MM * 4;
  float*    Lg    = (float*)ws;    ws += SZ_MM * 4;
  u16*      attn  = (u16*)ws;      ws += SZ_MM * 2;
  unsigned* RTs   = (unsigned*)ws; ws += SZ_MM * 4;
  u16*      Mb    = (u16*)ws;      ws += SZ_MM * 2;
  float*    Gp    = (float*)ws;    // kspl partials, last

  const long sXB = (long)CCH * NSP;       // xbf per-batch stride (u16 elems)
  const long sMM = (long)CCH * CCH;       // 384x384 in elements (u16/u32/f32)
  const long sM2 = (long)CCH * 768;       // split matrices viewed as u16

  transpose_kernel<<<dim3(NSPP / 64, CCH / 32, BATCH), dim3(256), 0, stream>>>(
      x, xt, xbf, probe);
  prep_kernel<<<dim3(1152), dim3(128), 0, stream>>>(
      w_qkv, b_qkv, gamma, beta, mean, var, b_proj, w_proj,
      w_eff, b_eff, bproj, w2qk, wp2, wvT, probe);
  zero_kernel<<<dim3(18), dim3(256), 0, stream>>>(
      (float4*)sx, (long)BATCH * (CCH + 768) / 4);   // sx + qn2 (contiguous)

  // Gram: Gp[b][kc] = xbf_b @ xbf_b^T (symmetric: n0>m0 skipped), fused row sums
  gemm_nt<128, 128, 2, 2, 1, false, false, 0, false, true, true>
      <<<dim3(3, 3, BATCH * kspl), dim3(256), 0, stream>>>(
      xbf, xbf, Gp, nullptr, nullptr,
      NSP, NSP, NSP, CCH, sXB, sXB, (long)kspl * sMM, sMM,
      0, 0, kspl, 0, nullptr, nullptr, sx, probe);

  greduce_kernel<<<dim3(576, BATCH), dim3(256), 0, stream>>>(Gp, Gs, kspl);
  ugemv_kernel<<<dim3(768, BATCH), dim3(64), 0, stream>>>(w_eff, sx, u);

  // T = W2qk @ Gs^T (K=768 hi/lo): split-bf16 out (rows<384 only) + fused norms
  gemm_nt<96, 96, 2, 2, 4, false, false, 3, true, false, false>
      <<<dim3(8, 4, BATCH), dim3(256), 0, stream>>>(
      (const u16*)w2qk, (const u16*)Gs, Ts, nullptr, nullptr,
      768, 768, 768, CCH, 0L, sM2, sMM, 0L,
      0, CCH, 1, 0, qn2, w_eff, nullptr, probe);

  // L = Tq @ Wk^T (K=768 hi/lo) -> fp32 raw logits
  gemm_nt<96, 96, 2, 2, 1, false, false, 0, false, false, false>
      <<<dim3(4, 4, BATCH), dim3(256), 0, stream>>>(
      (const u16*)Ts, (const u16*)w2qk + (long)384 * 768, Lg, nullptr, nullptr,
      768, 768, 768, CCH, sM2, 0L, sMM, 0L,
      0, 0, 1, 0, nullptr, nullptr, nullptr, probe);

  softmax_kernel<<<dim3(CCH, BATCH), dim3(128), 0, stream>>>(
      Lg, qn2, u, b_eff, temp, attn, av, probe);

  // RT = Wv^T @ attn^T = (attn @ Wv)^T -> split-bf16
  gemm_nt<96, 96, 2, 2, 4, false, false, 0, false, false, false>
      <<<dim3(4, 4, BATCH), dim3(256), 0, stream>>>(
      wvT, attn, RTs, nullptr, nullptr,
      CCH, CCH, CCH, CCH, 0L, sMM, sMM, 0L,
      0, 0, 1, 0, nullptr, nullptr, nullptr, probe);

  cgemv_kernel<<<dim3(CCH, BATCH), dim3(64), 0, stream>>>(wp2, av, bproj, cvec);

  // M = Wp @ RT^T = Wp @ attn @ Wv (K=768 hi/lo) -> bf16
  gemm_nt<96, 96, 2, 2, 0, false, false, 0, false, false, false>
      <<<dim3(4, 4, BATCH), dim3(256), 0, stream>>>(
      (const u16*)wp2, (const u16*)RTs, Mb, nullptr, nullptr,
      768, 768, 768, CCH, 0L, sM2, sMM, 0L,
      0, 0, 1, 0, nullptr, nullptr, nullptr, probe);

  // out = M @ x + cvec + x   (B = xt, residual = x, store n < 3136 only)
  gemm_nt<128, 128, 2, 2, 2, true, true, 2, false, false, false>
      <<<dim3(3, 25, BATCH), dim3(256), 0, stream>>>(
      Mb, xt, d_out, cvec, x,
      CCH, CCH, CCH, NSP, sMM, (long)NSPP * CCH, (long)CCH * NSP, (long)CCH * NSP,
      0, NSP, 1, CCH, nullptr, nullptr, nullptr, probe);
}

// Round 6
// 370.620 us; speedup vs baseline: 1.2635x; 1.0873x over previous
//
#include <hip/hip_runtime.h>

#define BATCH 16
#define CCH   384
#define NSP   3136
#define NSPP  3200   // xt rows padded to multiple of 128

typedef unsigned short u16;
typedef float  f32x4  __attribute__((ext_vector_type(4)));
typedef __bf16 bf16x8 __attribute__((ext_vector_type(8)));

__device__ __forceinline__ float bf2f(u16 u) {
  union { unsigned int i; float f; } v; v.i = ((unsigned int)u) << 16; return v.f;
}
__device__ __forceinline__ u16 f2bf(float f) {
  union { float f; unsigned int i; } v; v.f = f;
  unsigned int i = v.i;
  return (u16)((i + 0x7fffu + ((i >> 16) & 1u)) >> 16);
}
__device__ __forceinline__ float rdf(const void* p, long i, bool bf) {
  return bf ? bf2f(((const u16*)p)[i]) : ((const float*)p)[i];
}

// direct global->LDS DMA, 16B per lane. LDS dest is wave-uniform base + lane*16.
__device__ __forceinline__ void gload_lds16(const u16* g, u16* l) {
  __builtin_amdgcn_global_load_lds(
      (const __attribute__((address_space(1))) void*)g,
      (__attribute__((address_space(3))) void*)l, 16, 0, 0);
}

// ------- x[b][c][n] -> xt[b][n][c] bf16 (n padded to NSPP) AND xbf[b][c][n] ---
__global__ void transpose_kernel(const void* __restrict__ x, u16* __restrict__ xt,
                                 u16* __restrict__ xbf, const u16* __restrict__ probe) {
  const bool bf = (probe[0] == 0x3F80u);
  __shared__ float Ls[32 * 65];
  const int t = threadIdx.x;
  const int n0 = blockIdx.x * 64, c0 = blockIdx.y * 32, b = blockIdx.z;
  if (n0 >= NSP) {  // pure pad tile (3136 = 49*64, tiles never straddle)
    const int n_l = t >> 2, c8 = (t & 3) * 8;
    uint4 zq = make_uint4(0, 0, 0, 0);
    *(uint4*)(xt + ((long)b * NSPP + n0 + n_l) * CCH + c0 + c8) = zq;
    return;
  }
  {
    const int c_l = t >> 3, n8 = (t & 7) * 8;
    const long src = ((long)b * CCH + c0 + c_l) * NSP + n0 + n8;
    float v[8];
    if (bf) {
      union { uint4 q; u16 e[8]; } u; u.q = *(const uint4*)((const u16*)x + src);
      #pragma unroll
      for (int i = 0; i < 8; i++) v[i] = bf2f(u.e[i]);
    } else {
      float4 a = *(const float4*)((const float*)x + src);
      float4 c = *(const float4*)((const float*)x + src + 4);
      v[0]=a.x; v[1]=a.y; v[2]=a.z; v[3]=a.w; v[4]=c.x; v[5]=c.y; v[6]=c.z; v[7]=c.w;
    }
    union { uint4 q; u16 e[8]; } ob;
    #pragma unroll
    for (int i = 0; i < 8; i++) { ob.e[i] = f2bf(v[i]); Ls[c_l * 65 + n8 + i] = v[i]; }
    *(uint4*)(xbf + src) = ob.q;   // bf16 copy in native [c][n] layout (for Gram)
  }
  __syncthreads();
  {
    const int n_l = t >> 2, c8 = (t & 3) * 8;
    union { uint4 q; u16 e[8]; } o;
    #pragma unroll
    for (int i = 0; i < 8; i++) o.e[i] = f2bf(Ls[(c8 + i) * 65 + n_l]);
    *(uint4*)(xt + ((long)b * NSPP + n0 + n_l) * CCH + c0 + c8) = o.q;
  }
}

// ------- prep: BN-fold qkv weights; doubled-column (hi/lo K) weight copies ----
// Also zeroes the sums region (sx + qn2, 72*256 floats) in blocks o < 72.
__global__ void prep_kernel(const void* __restrict__ w_qkv, const void* __restrict__ b_qkv,
                            const void* __restrict__ gamma, const void* __restrict__ beta,
                            const void* __restrict__ mean,  const void* __restrict__ var,
                            const void* __restrict__ b_proj, const void* __restrict__ w_proj,
                            u16* __restrict__ w_eff, float* __restrict__ b_eff,
                            float* __restrict__ bproj_f,
                            unsigned* __restrict__ w2qk, unsigned* __restrict__ wp2,
                            u16* __restrict__ wvT, float* __restrict__ szero,
                            const u16* __restrict__ probe) {
  const bool bf = (probe[0] == 0x3F80u);
  __shared__ float s_scale[CCH], s_shift[CCH];
  const int tid = threadIdx.x;  // 128
  const int o = blockIdx.x;  // [0,1152)
  if (o < 72) {  // zero sx (16*384) + qn2 (16*768) = 18432 floats
    szero[o * 256 + tid] = 0.f;
    szero[o * 256 + 128 + tid] = 0.f;
  }
  for (int c = tid; c < CCH; c += 128) {
    float g = rdf(gamma, c, bf), bt = rdf(beta, c, bf);
    float mn = rdf(mean, c, bf), vr = rdf(var, c, bf);
    float sc = g * rsqrtf(vr + 1e-5f);
    s_scale[c] = sc; s_shift[c] = bt - mn * sc;
  }
  __syncthreads();
  float part = 0.f;
  for (int c = tid; c < CCH; c += 128) {
    float w = rdf(w_qkv, (long)o * CCH + c, bf);
    u16 wv = f2bf(w * s_scale[c]);
    w_eff[(long)o * CCH + c] = wv;
    if (o < 768) w2qk[(long)o * CCH + c] = (unsigned)wv | ((unsigned)wv << 16);
    else         wvT[(long)c * CCH + (o - 768)] = wv;   // Wv^T
    part += w * s_shift[c];
  }
  for (int off = 32; off > 0; off >>= 1) part += __shfl_down(part, off, 64);
  __shared__ float s_part[2];
  if ((tid & 63) == 0) s_part[tid >> 6] = part;
  __syncthreads();
  if (tid == 0) b_eff[o] = rdf(b_qkv, o, bf) + s_part[0] + s_part[1];
  if (o < CCH) {
    for (int c = tid; c < CCH; c += 128) {
      u16 pv = f2bf(rdf(w_proj, (long)o * CCH + c, bf));
      wp2[(long)o * CCH + c] = (unsigned)pv | ((unsigned)pv << 16);
    }
  }
  if (o == 0) {
    for (int c = tid; c < CCH; c += 128) bproj_f[c] = rdf(b_proj, c, bf);
  }
}

// ------- generic NT GEMM: C(MxN) = A(MxK) @ B(NxK)^T --------------------------
// Round-3 proven loop: single-buffer, global_load_lds dwordx4, pre-XOR-swizzled
// source, 2 barriers/k-step. XCD-bijective swizzle.
// RES: residual is PREFETCHED into VGPRs before the k-loop (issue-early /
// consume-late): the 64 scattered loads retire under the 6 k-steps instead of
// serializing the epilogue.
// OUTM: 0 bf16 | 1 fp32 (+kc*sRes partial when ks>1) | 2 adaptive | 4 split-bf16
//       (hi,lo u16 pair packed in u32; ldc/sC in u32 units).
// NCHK: 0 none | 2 skip store/res for nn>=nLim | 3 skip store for mm>=nLim.
// EPIL: row dot  qns[(zb+z)*768+mm] += sum_nn v * epW[mm*384+nn]   (norms).
// SUMX: fused A-row sums (n0==0 blocks) -> sxp[z*384+row]          (Gram).
// SYMM: skip blocks with n0 > m0 (symmetric output; consumer mirrors).
template<int BM, int BN, int WGM, int WGN, int OUTM, bool BIASM, bool RES,
         int NCHK, bool EPIL, bool SUMX, bool SYMM>
__launch_bounds__(256)
__global__ void gemm_nt(const u16* __restrict__ A, const u16* __restrict__ B,
                        void* __restrict__ Cv,
                        const float* __restrict__ biasm,
                        const void* __restrict__ resv,
                        int K, int lda, int ldb, int ldc,
                        long sA, long sB, long sC, long sRes,
                        int zb, int nLim, int ks, int sBM,
                        float* __restrict__ qns, const u16* __restrict__ epW,
                        float* __restrict__ sxp,
                        const u16* __restrict__ probe) {
  constexpr int WM = BM / WGM, WN = BN / WGN;
  constexpr int FM = WM / 16,  FN = WN / 16;
  constexpr int NA = BM / 32,  NB = BN / 32;
  const bool f32io = (probe[0] != 0x3F80u);
  __shared__ __align__(16) u16 As[BM * 64];
  __shared__ __align__(16) u16 Bs[BN * 64];
  const int tid = threadIdx.x, wave = tid >> 6, lane = tid & 63;
  const int quad = lane >> 4, l16 = lane & 15;
  const int wm = wave / WGN, wn = wave % WGN;
  int z = blockIdx.z, kc = 0;
  if (ks > 1) { kc = z % ks; z /= ks; }
  A += z * sA; B += z * sB;
  const long cOff = (long)(zb + z) * sC;
  const long rOff = (long)(zb + z) * sRes;

  const int gx = gridDim.x;
  const int tot = gx * gridDim.y;
  const int wg = blockIdx.y * gx + blockIdx.x;
  const int qq = tot >> 3, rr = tot & 7;
  const int xcd = wg & 7, idx = wg >> 3;
  const int nid = (xcd < rr ? xcd * (qq + 1) : rr * (qq + 1) + (xcd - rr) * qq) + idx;
  const int m0 = (nid % gx) * BM, n0 = (nid / gx) * BN;
  if (SYMM && n0 > m0) return;

  const int kLen = K / ks, kBeg = kc * kLen;

  const u16* ag[NA];
  const u16* bg[NB];
  #pragma unroll
  for (int p = 0; p < NA; p++) {
    int u = tid + p * 256, r = u >> 3, k8 = u & 7;
    ag[p] = A + (long)(m0 + r) * lda + kBeg + ((k8 ^ (r & 7)) << 3);
  }
  #pragma unroll
  for (int p = 0; p < NB; p++) {
    int u = tid + p * 256, r = u >> 3, k8 = u & 7;
    bg[p] = B + (long)(n0 + r) * ldb + kBeg + ((k8 ^ (r & 7)) << 3);
  }

  // residual prefetch: issue all loads now; they complete during the k-loop.
  float rpre[FM][FN][4];
  if (RES) {
    #pragma unroll
    for (int f = 0; f < FM; f++)
      #pragma unroll
      for (int g = 0; g < FN; g++)
        #pragma unroll
        for (int reg = 0; reg < 4; reg++) {
          const int mm = m0 + wm * WM + f * 16 + quad * 4 + reg;
          const int nn = n0 + wn * WN + g * 16 + l16;
          const bool live = (NCHK != 2) || (nn < nLim);
          const long ro = rOff + (long)mm * ldc + nn;
          rpre[f][g][reg] = live
              ? (f32io ? ((const float*)resv)[ro] : bf2f(((const u16*)resv)[ro]))
              : 0.f;
        }
  }

  f32x4 acc[FM][FN] = {};
  float rs[FM] = {};   // SUMX accumulators

  const int nt = kLen >> 6;
  for (int t = 0; t < nt; t++) {
    #pragma unroll
    for (int p = 0; p < NA; p++) { gload_lds16(ag[p], &As[(p * 256 + wave * 64) * 8]); ag[p] += 64; }
    #pragma unroll
    for (int p = 0; p < NB; p++) { gload_lds16(bg[p], &Bs[(p * 256 + wave * 64) * 8]); bg[p] += 64; }
    __syncthreads();

    #pragma unroll
    for (int tt = 0; tt < 2; tt++) {
      bf16x8 af[FM], bfr[FN];
      #pragma unroll
      for (int f = 0; f < FM; f++) {
        int r = wm * WM + f * 16 + l16;
        af[f] = *(const bf16x8*)&As[r * 64 + (((tt * 4 + quad) ^ (l16 & 7)) << 3)];
      }
      #pragma unroll
      for (int g = 0; g < FN; g++) {
        int r = wn * WN + g * 16 + l16;
        bfr[g] = *(const bf16x8*)&Bs[r * 64 + (((tt * 4 + quad) ^ (l16 & 7)) << 3)];
      }
      if (SUMX) {
        if (n0 == 0 && wn == 0) {
          #pragma unroll
          for (int f = 0; f < FM; f++)
            #pragma unroll
            for (int j = 0; j < 8; j++) rs[f] += (float)af[f][j];
        }
      }
      #pragma unroll
      for (int f = 0; f < FM; f++)
        #pragma unroll
        for (int g = 0; g < FN; g++)
          acc[f][g] = __builtin_amdgcn_mfma_f32_16x16x32_bf16(af[f], bfr[g], acc[f][g], 0, 0, 0);
    }
    __syncthreads();
  }

  if (SUMX) {
    if (n0 == 0 && wn == 0) {
      #pragma unroll
      for (int f = 0; f < FM; f++) {
        float r = rs[f];
        r += __shfl_xor(r, 16, 64);
        r += __shfl_xor(r, 32, 64);
        if (quad == 0) atomicAdd(sxp + (long)z * CCH + m0 + wm * WM + f * 16 + l16, r);
      }
    }
  }

  #pragma unroll
  for (int f = 0; f < FM; f++) {
    #pragma unroll
    for (int reg = 0; reg < 4; reg++) {
      const int mm = m0 + wm * WM + f * 16 + quad * 4 + reg;
      float s2 = 0.f;
      #pragma unroll
      for (int g = 0; g < FN; g++) {
        int nn = n0 + wn * WN + g * 16 + l16;
        float v = acc[f][g][reg];
        if (BIASM) v += biasm[(long)(zb + z) * sBM + mm];
        long off = (long)mm * ldc + nn;
        bool live = true;
        if (NCHK == 2) live = (nn < nLim);
        if (NCHK == 3) live = (mm < nLim);
        if (RES) v += rpre[f][g][reg];
        if (EPIL) s2 += v * bf2f(epW[(long)mm * CCH + nn]);
        if (OUTM == 1) {
          ((float*)Cv)[cOff + off + (long)kc * sRes] = v;
        } else if (OUTM == 2) {
          if (live) {
            if (f32io) ((float*)Cv)[cOff + off] = v;
            else       ((u16*)Cv)[cOff + off]   = f2bf(v);
          }
        } else if (OUTM == 4) {
          if (live) {
            u16 hi = f2bf(v);
            u16 lo = f2bf(v - bf2f(hi));
            ((unsigned*)Cv)[cOff + off] = (unsigned)hi | ((unsigned)lo << 16);
          }
        } else {
          if (live) ((u16*)Cv)[cOff + off] = f2bf(v);
        }
      }
      if (EPIL) {
        s2 += __shfl_xor(s2, 1, 16);
        s2 += __shfl_xor(s2, 2, 16);
        s2 += __shfl_xor(s2, 4, 16);
        s2 += __shfl_xor(s2, 8, 16);
        if (l16 == 0) atomicAdd(qns + (long)(zb + z) * 768 + mm, s2);
      }
    }
  }
}

// ------- fused: Gram reduce (split-bf16 G) + u = w_eff @ sx -------------------
__global__ void gred_ugemv_kernel(const float* __restrict__ Gp, unsigned* __restrict__ Gs,
                                  const u16* __restrict__ w_eff, const float* __restrict__ sx,
                                  float* __restrict__ u, int kspl) {
  const int b = blockIdx.y, bx = blockIdx.x, tid = threadIdx.x;
  if (bx < 576) {
    const int idx = bx * 256 + tid;  // < 384*384
    const int r = idx / CCH, c = idx % CCH;
    const long e = ((r >> 7) >= (c >> 7)) ? ((long)r * CCH + c) : ((long)c * CCH + r);
    const long base = (long)b * kspl * (CCH * CCH);
    float s = 0.f;
    for (int k = 0; k < kspl; k++) s += Gp[base + (long)k * (CCH * CCH) + e];
    u16 hi = f2bf(s);
    u16 lo = f2bf(s - bf2f(hi));
    Gs[(long)b * (CCH * CCH) + idx] = (unsigned)hi | ((unsigned)lo << 16);
  } else {
    const int m = (bx - 576) * 4 + (tid >> 6), l = tid & 63;  // 4 rows/block
    float s = 0.f;
    for (int k = l; k < CCH; k += 64) s += bf2f(w_eff[(long)m * CCH + k]) * sx[b * CCH + k];
    for (int off = 32; off > 0; off >>= 1) s += __shfl_down(s, off, 64);
    if (l == 0) u[b * 768 + m] = s;
  }
}

// ------- cvec[b][o] = sum_c wp[o][c]*av[b][c] + bproj[o] ----------------------
__global__ void cgemv_kernel(const unsigned* __restrict__ wp2, const float* __restrict__ av,
                             const float* __restrict__ bproj, float* __restrict__ cvec) {
  const int o = blockIdx.x, b = blockIdx.y, l = threadIdx.x;  // 64
  float s = 0.f;
  for (int c = l; c < CCH; c += 64)
    s += bf2f((u16)(wp2[(long)o * CCH + c] & 0xffffu)) * av[b * CCH + c];
  for (int off = 32; off > 0; off >>= 1) s += __shfl_down(s, off, 64);
  if (l == 0) cvec[b * CCH + o] = s + bproj[o];
}

// ------- softmax over d with bias rank-1 terms + norm/temperature scaling -----
__global__ void softmax_kernel(const float* __restrict__ Lg, const float* __restrict__ qn2,
                               const float* __restrict__ u, const float* __restrict__ beff,
                               const void* __restrict__ temp,
                               u16* __restrict__ attn, float* __restrict__ av,
                               const u16* __restrict__ probe) {
  const bool bfm = (probe[0] == 0x3F80u);
  const int c = blockIdx.x, b = blockIdx.y, tid = threadIdx.x;  // 128
  const float* row = Lg + ((long)b * CCH + c) * CCH;
  const float beq = beff[c], uq = u[b * 768 + c];
  const float qn = qn2[b * 768 + c] + 2.f * beq * uq + 3136.f * beq * beq;
  const float rq = 1.f / fmaxf(sqrtf(fmaxf(qn, 0.f)), 1e-12f);
  const float T = rdf(temp, 0, bfm);
  float v[3]; float mx = -1e30f;
  #pragma unroll
  for (int j = 0; j < 3; j++) {
    int d = tid + j * 128;
    float bek = beff[384 + d], uk = u[b * 768 + 384 + d];
    float kn = qn2[b * 768 + 384 + d] + 2.f * bek * uk + 3136.f * bek * bek;
    float rd = 1.f / fmaxf(sqrtf(fmaxf(kn, 0.f)), 1e-12f);
    float lg = row[d] + uq * bek + beq * uk + 3136.f * beq * bek;
    v[j] = lg * rq * rd * T;
    mx = fmaxf(mx, v[j]);
  }
  for (int off = 32; off > 0; off >>= 1) mx = fmaxf(mx, __shfl_down(mx, off, 64));
  __shared__ float sm[2];
  if ((tid & 63) == 0) sm[tid >> 6] = mx;
  __syncthreads();
  mx = fmaxf(sm[0], sm[1]);
  float s = 0.f;
  #pragma unroll
  for (int j = 0; j < 3; j++) { v[j] = __expf(v[j] - mx); s += v[j]; }
  for (int off = 32; off > 0; off >>= 1) s += __shfl_down(s, off, 64);
  __shared__ float ss[2];
  if ((tid & 63) == 0) ss[tid >> 6] = s;
  __syncthreads();
  s = ss[0] + ss[1];
  const float inv = 1.f / s;
  float avp = 0.f;
  u16* arow = attn + ((long)b * CCH + c) * CCH;
  #pragma unroll
  for (int j = 0; j < 3; j++) {
    float p = v[j] * inv;
    arow[tid + j * 128] = f2bf(p);
    avp += p * beff[768 + tid + j * 128];
  }
  for (int off = 32; off > 0; off >>= 1) avp += __shfl_down(avp, off, 64);
  __shared__ float sa[2];
  if ((tid & 63) == 0) sa[tid >> 6] = avp;
  __syncthreads();
  if (tid == 0) av[b * CCH + c] = sa[0] + sa[1];
}

// ------- launcher -------------------------------------------------------------
extern "C" void kernel_launch(void* const* d_in, const int* in_sizes, int n_in,
                              void* d_out, int out_size, void* d_ws, size_t ws_size,
                              hipStream_t stream) {
  const void* x      = d_in[0];
  const void* w_qkv  = d_in[1];
  const void* b_qkv  = d_in[2];
  const void* w_proj = d_in[3];
  const void* b_proj = d_in[4];
  const void* gamma  = d_in[5];
  const void* beta   = d_in[6];
  const void* mean   = d_in[7];
  const void* var    = d_in[8];
  const void* temp   = d_in[9];
  const u16* probe = (const u16*)gamma;  // bf16 1.0 -> 0x3F80; fp32 low word -> 0

  const size_t SZ_XT   = (size_t)BATCH * NSPP * CCH * 2;       // 39.3 MB
  const size_t SZ_XBF  = (size_t)BATCH * CCH * NSP * 2;        // 38.5 MB
  const size_t SZ_WEFF = (size_t)1152 * CCH * 2;
  const size_t SZ_W2QK = (size_t)768 * CCH * 4;                // u32 dup pairs
  const size_t SZ_WP2  = (size_t)CCH * CCH * 4;
  const size_t SZ_WVT  = (size_t)CCH * CCH * 2;
  const size_t SZ_BEFF = (size_t)1152 * 4;
  const size_t SZ_BPRJ = (size_t)CCH * 4;
  const size_t SZ_U    = (size_t)BATCH * 768 * 4;
  const size_t SZ_AV   = (size_t)BATCH * CCH * 4;
  const size_t SZ_CV   = (size_t)BATCH * CCH * 4;
  const size_t SZ_MM   = (size_t)BATCH * CCH * CCH;            // 384x384 per b, x1B unit
  const size_t FIXED = SZ_XT + SZ_XBF + SZ_WEFF + SZ_W2QK + SZ_WP2 + SZ_WVT +
                       SZ_BEFF + SZ_BPRJ + (size_t)BATCH * (CCH + 768) * 4 +
                       SZ_U + SZ_AV + SZ_CV +
                       SZ_MM * 4 /*Gs*/ + SZ_MM * 4 /*Ts*/ + SZ_MM * 4 /*L*/ +
                       SZ_MM * 2 /*attn*/ + SZ_MM * 4 /*RTs*/ + SZ_MM * 2 /*Mb*/;
  int kspl = 7;  // must divide 49 k-steps
  if (ws_size < FIXED + (size_t)BATCH * 7 * CCH * CCH * 4) kspl = 1;

  char* ws = (char*)d_ws;
  u16*      xt    = (u16*)ws;      ws += SZ_XT;
  u16*      xbf   = (u16*)ws;      ws += SZ_XBF;
  u16*      w_eff = (u16*)ws;      ws += SZ_WEFF;
  unsigned* w2qk  = (unsigned*)ws; ws += SZ_W2QK;
  unsigned* wp2   = (unsigned*)ws; ws += SZ_WP2;
  u16*      wvT   = (u16*)ws;      ws += SZ_WVT;
  float*    b_eff = (float*)ws;    ws += SZ_BEFF;
  float*    bproj = (float*)ws;    ws += SZ_BPRJ;
  float*    sx    = (float*)ws;    ws += (size_t)BATCH * CCH * 4;
  float*    qn2   = (float*)ws;    ws += (size_t)BATCH * 768 * 4;
  float*    u     = (float*)ws;    ws += SZ_U;
  float*    av    = (float*)ws;    ws += SZ_AV;
  float*    cvec  = (float*)ws;    ws += SZ_CV;
  unsigned* Gs    = (unsigned*)ws; ws += SZ_MM * 4;
  unsigned* Ts    = (unsigned*)ws; ws += SZ_MM * 4;
  float*    Lg    = (float*)ws;    ws += SZ_MM * 4;
  u16*      attn  = (u16*)ws;      ws += SZ_MM * 2;
  unsigned* RTs   = (unsigned*)ws; ws += SZ_MM * 4;
  u16*      Mb    = (u16*)ws;      ws += SZ_MM * 2;
  float*    Gp    = (float*)ws;    // kspl partials, last

  const long sXB = (long)CCH * NSP;       // xbf per-batch stride (u16 elems)
  const long sMM = (long)CCH * CCH;       // 384x384 in elements (u16/u32/f32)
  const long sM2 = (long)CCH * 768;       // split matrices viewed as u16

  transpose_kernel<<<dim3(NSPP / 64, CCH / 32, BATCH), dim3(256), 0, stream>>>(
      x, xt, xbf, probe);
  prep_kernel<<<dim3(1152), dim3(128), 0, stream>>>(
      w_qkv, b_qkv, gamma, beta, mean, var, b_proj, w_proj,
      w_eff, b_eff, bproj, w2qk, wp2, wvT, sx, probe);

  // Gram: Gp[b][kc] = xbf_b @ xbf_b^T (symmetric: n0>m0 skipped), fused row sums
  gemm_nt<128, 128, 2, 2, 1, false, false, 0, false, true, true>
      <<<dim3(3, 3, BATCH * kspl), dim3(256), 0, stream>>>(
      xbf, xbf, Gp, nullptr, nullptr,
      NSP, NSP, NSP, CCH, sXB, sXB, (long)kspl * sMM, sMM,
      0, 0, kspl, 0, nullptr, nullptr, sx, probe);

  // fused: G split-bf16 reduce + u = w_eff @ sx
  gred_ugemv_kernel<<<dim3(768, BATCH), dim3(256), 0, stream>>>(
      Gp, Gs, w_eff, sx, u, kspl);

  // T = W2qk @ Gs^T (K=768 hi/lo): split-bf16 out (rows<384 only) + fused norms
  gemm_nt<96, 96, 2, 2, 4, false, false, 3, true, false, false>
      <<<dim3(8, 4, BATCH), dim3(256), 0, stream>>>(
      (const u16*)w2qk, (const u16*)Gs, Ts, nullptr, nullptr,
      768, 768, 768, CCH, 0L, sM2, sMM, 0L,
      0, CCH, 1, 0, qn2, w_eff, nullptr, probe);

  // L = Tq @ Wk^T (K=768 hi/lo) -> fp32 raw logits
  gemm_nt<96, 96, 2, 2, 1, false, false, 0, false, false, false>
      <<<dim3(4, 4, BATCH), dim3(256), 0, stream>>>(
      (const u16*)Ts, (const u16*)w2qk + (long)384 * 768, Lg, nullptr, nullptr,
      768, 768, 768, CCH, sM2, 0L, sMM, 0L,
      0, 0, 1, 0, nullptr, nullptr, nullptr, probe);

  softmax_kernel<<<dim3(CCH, BATCH), dim3(128), 0, stream>>>(
      Lg, qn2, u, b_eff, temp, attn, av, probe);

  // RT = Wv^T @ attn^T = (attn @ Wv)^T -> split-bf16
  gemm_nt<96, 96, 2, 2, 4, false, false, 0, false, false, false>
      <<<dim3(4, 4, BATCH), dim3(256), 0, stream>>>(
      wvT, attn, RTs, nullptr, nullptr,
      CCH, CCH, CCH, CCH, 0L, sMM, sMM, 0L,
      0, 0, 1, 0, nullptr, nullptr, nullptr, probe);

  cgemv_kernel<<<dim3(CCH, BATCH), dim3(64), 0, stream>>>(wp2, av, bproj, cvec);

  // M = Wp @ RT^T = Wp @ attn @ Wv (K=768 hi/lo) -> bf16
  gemm_nt<96, 96, 2, 2, 0, false, false, 0, false, false, false>
      <<<dim3(4, 4, BATCH), dim3(256), 0, stream>>>(
      (const u16*)wp2, (const u16*)RTs, Mb, nullptr, nullptr,
      768, 768, 768, CCH, 0L, sM2, sMM, 0L,
      0, 0, 1, 0, nullptr, nullptr, nullptr, probe);

  // out = M @ x + cvec + x   (B = xt, residual = x prefetched, store n < 3136)
  gemm_nt<128, 128, 2, 2, 2, true, true, 2, false, false, false>
      <<<dim3(3, 25, BATCH), dim3(256), 0, stream>>>(
      Mb, xt, d_out, cvec, x,
      CCH, CCH, CCH, NSP, sMM, (long)NSPP * CCH, (long)CCH * NSP, (long)CCH * NSP,
      0, NSP, 1, CCH, nullptr, nullptr, nullptr, probe);
}